// Round 15
// baseline (77.739 us; speedup 1.0000x reference)
//
#include <hip/hip_runtime.h>
#include <hip/hip_bf16.h>
#include <math.h>

#define N_CLASS 200000
#define DIM     192
#define BATCH   64
#define NSLOT   3
#define M_ROWS  192            // B*N
#define GRID_M  1024           // 4 blocks x 256 CUs, all co-resident
// 12500 16-class tiles = 1024*12 + 212

#define S_SCALE 30.0f
#define COS_M   0.9800665778412416f
#define SIN_M   0.19866933079506122f
#define TH_C    (-0.9800665778412416f)
#define MM_C    0.039733866159012245f

typedef __attribute__((ext_vector_type(8))) short bf16x8;
typedef __attribute__((ext_vector_type(4))) float f32x4;

__device__ __forceinline__ float wave_reduce_sum(float v) {
#pragma unroll
    for (int o = 32; o > 0; o >>= 1) v += __shfl_xor(v, o, 64);
    return v;
}

__device__ __forceinline__ unsigned short f2bf(float f) {
    union { __hip_bfloat16 h; unsigned short u; } v;
    v.h = __float2bfloat16(f);
    return v.u;
}

__device__ __forceinline__ bf16x8 pack8(float4 a, float4 b) {
    bf16x8 r;
    r[0] = (short)f2bf(a.x); r[1] = (short)f2bf(a.y);
    r[2] = (short)f2bf(a.z); r[3] = (short)f2bf(a.w);
    r[4] = (short)f2bf(b.x); r[5] = (short)f2bf(b.y);
    r[6] = (short)f2bf(b.z); r[7] = (short)f2bf(b.w);
    return r;
}

__device__ __forceinline__ void gload_lds16(const void* g, void* l) {
    __builtin_amdgcn_global_load_lds(
        (const __attribute__((address_space(1))) unsigned int*)g,
        (__attribute__((address_space(3))) unsigned int*)l, 16, 0, 0);
}

// ---- normalize pred_embs -> xn fp32 [row][k] and xbf bf16 [row][k] ----
__global__ void k_normalize(const float* __restrict__ pe,
                            float* __restrict__ xn, unsigned short* __restrict__ xbf) {
    int r = blockIdx.x;      // 0..191
    int l = threadIdx.x;     // 0..63
    float v0 = pe[r * DIM + l];
    float v1 = pe[r * DIM + l + 64];
    float v2 = pe[r * DIM + l + 128];
    float ss = wave_reduce_sum(v0 * v0 + v1 * v1 + v2 * v2);
    float rn = 1.0f / fmaxf(sqrtf(ss), 1e-6f);
    float a0 = v0 * rn, a1 = v1 * rn, a2 = v2 * rn;
    xn[r * DIM + l]       = a0;
    xn[r * DIM + l + 64]  = a1;
    xn[r * DIM + l + 128] = a2;
    xbf[r * DIM + l]       = f2bf(a0);
    xbf[r * DIM + l + 64]  = f2bf(a1);
    xbf[r * DIM + l + 128] = f2bf(a2);
}

// ---- gt-label cosines in exact fp32 ----
__global__ void k_gtcos(const float* __restrict__ weight, const int* __restrict__ gt,
                        const float* __restrict__ xn, float* __restrict__ cosl) {
    int i = blockIdx.x;             // b*S + s
    int b = i / NSLOT, s = i - b * NSLOT;
    int l = threadIdx.x;
    int lab = gt[b * NSLOT + s];
    const float* w = weight + (long)lab * DIM;
    float w0 = w[l], w1 = w[l + 64], w2 = w[l + 128];
    float ss = wave_reduce_sum(w0 * w0 + w1 * w1 + w2 * w2);
    float rn = 1.0f / fmaxf(sqrtf(ss), 1e-6f);
    for (int n = 0; n < NSLOT; ++n) {
        const float* x = xn + (b * NSLOT + n) * DIM;
        float d = wave_reduce_sum(w0 * x[l] + w1 * x[l + 64] + w2 * x[l + 128]);
        float c = fminf(fmaxf(d * rn, -1.0f + 1e-7f), 1.0f - 1e-7f);
        if (l == 0) cosl[(b * NSLOT + n) * NSLOT + s] = c;
    }
}

// ---- MFMA GEMM: 256-thr blocks, 4 blocks/CU, W LDS ring-6 depth-5 ----
// Waves = 4 row-groups(48 rows) x 1 class-group(16 classes/tile).
// launch_bounds(256,2): no VGPR clamp. A-frags direct from global (once).
// W: ring-6 x 4KB, depth-5 counted vmcnt(4), 1 load/thread/phase.
// 4 resident blocks/CU interleave barrier stalls; 80 KB in flight/CU.
__global__ __launch_bounds__(256, 2)
void k_main(const float* __restrict__ weight,
            const unsigned short* __restrict__ xbf,
            float* __restrict__ partials) {
    __shared__ __align__(16) char smem[6 * 4096];   // 24 KB ring

    const int tid  = threadIdx.x;
    const int lane = tid & 63;
    const int rg   = tid >> 6;      // 0..3 -> rows rg*48..+47
    const int lr   = lane & 15;     // class in tile
    const int q    = lane >> 4;     // k-quad
    const int bid  = blockIdx.x;

    const int ntile = 12 + (bid < 212 ? 1 : 0);   // 12500 = 1024*12 + 212
    const int nst   = ntile * 3;

    // ---- A fragments direct from global (once) ----
    bf16x8 areg[3][6];
#pragma unroll
    for (int t = 0; t < 3; ++t) {
        const unsigned short* xp = xbf + (rg * 48 + t * 16 + lr) * DIM + q * 8;
#pragma unroll
        for (int s = 0; s < 6; ++s)
            areg[t][s] = *reinterpret_cast<const bf16x8*>(xp + s * 32);
    }

    // ---- W pipeline (depth 5, ring 6), tiles of 16 classes ----
    const int row_w = tid >> 4, pc_w = tid & 15;
    const long tstride = (long)GRID_M * 16 * DIM;  // floats between my tiles
    const float* gW0 = weight + (long)bid * 16 * DIM
                     + row_w * DIM + ((pc_w ^ (row_w & 7)) << 2);

    // prologue: issue phases 0..4 (tile kp: 0/0,0/1,0/2,1/0,1/1)
    gload_lds16(gW0,                  smem + 0 * 4096 + tid * 16);
    gload_lds16(gW0 + 64,             smem + 1 * 4096 + tid * 16);
    gload_lds16(gW0 + 128,            smem + 2 * 4096 + tid * 16);
    gload_lds16(gW0 + tstride,        smem + 3 * 4096 + tid * 16);
    gload_lds16(gW0 + tstride + 64,   smem + 4 * 4096 + tid * 16);
    long goff  = tstride + 128;                   // next issue: tile 1, kp 2
    int  kp_is = 2;
    int  si = 5, sc = 0;                          // issue slot, compute slot

    f32x4 acc[3];
#pragma unroll
    for (int t = 0; t < 3; ++t) acc[t] = (f32x4){0.f, 0.f, 0.f, 0.f};
    float rs[3][4];
#pragma unroll
    for (int t = 0; t < 3; ++t)
#pragma unroll
        for (int r = 0; r < 4; ++r) rs[t][r] = 0.f;
    float sq = 0.f;

    const int wrow16 = lr * 16;                    // float4 base of class row
    const int wx     = lr & 7;

#define PHASE(KP)                                                              \
    {                                                                          \
        int g = j * 3 + KP;                                                    \
        int rem = nst - 1 - g;                                                 \
        if (rem >= 4)      asm volatile("s_waitcnt vmcnt(4)" ::: "memory");    \
        else if (rem == 3) asm volatile("s_waitcnt vmcnt(3)" ::: "memory");    \
        else if (rem == 2) asm volatile("s_waitcnt vmcnt(2)" ::: "memory");    \
        else if (rem == 1) asm volatile("s_waitcnt vmcnt(1)" ::: "memory");    \
        else               asm volatile("s_waitcnt vmcnt(0)" ::: "memory");    \
        __builtin_amdgcn_s_barrier();                                          \
        __builtin_amdgcn_sched_barrier(0);                                     \
        if (g + 5 < nst) {                                                     \
            gload_lds16(gW0 + goff, smem + si * 4096 + tid * 16);              \
            si = (si == 5) ? 0 : si + 1;                                       \
            if (kp_is == 2) { kp_is = 0; goff += tstride - 128; }              \
            else            { ++kp_is;   goff += 64; }                         \
        }                                                                      \
        const float4* Wc = (const float4*)(smem + sc * 4096);                  \
        sc = (sc == 5) ? 0 : sc + 1;                                           \
        _Pragma("unroll")                                                      \
        for (int ks = 0; ks < 2; ++ks) {                                       \
            int c1 = ks * 8 + 2 * q;                                           \
            float4 wv1 = Wc[wrow16 + (c1 ^ wx)];                               \
            float4 wv2 = Wc[wrow16 + ((c1 + 1) ^ wx)];                         \
            sq += wv1.x*wv1.x + wv1.y*wv1.y + wv1.z*wv1.z + wv1.w*wv1.w        \
                + wv2.x*wv2.x + wv2.y*wv2.y + wv2.z*wv2.z + wv2.w*wv2.w;       \
            bf16x8 bb = pack8(wv1, wv2);                                       \
            acc[0] = __builtin_amdgcn_mfma_f32_16x16x32_bf16(                  \
                         areg[0][KP * 2 + ks], bb, acc[0], 0, 0, 0);           \
            acc[1] = __builtin_amdgcn_mfma_f32_16x16x32_bf16(                  \
                         areg[1][KP * 2 + ks], bb, acc[1], 0, 0, 0);           \
            acc[2] = __builtin_amdgcn_mfma_f32_16x16x32_bf16(                  \
                         areg[2][KP * 2 + ks], bb, acc[2], 0, 0, 0);           \
        }                                                                      \
    }

#pragma unroll 1
    for (int j = 0; j < ntile; ++j) {
        PHASE(0)
        PHASE(1)
        PHASE(2)
        // ---- per-tile epilogue: class norm + exp accumulation ----
        float s2 = sq;
        s2 += __shfl_xor(s2, 16); s2 += __shfl_xor(s2, 32);
        float rn = 1.0f / fmaxf(sqrtf(s2), 1e-6f);
#pragma unroll
        for (int t = 0; t < 3; ++t)
#pragma unroll
            for (int r = 0; r < 4; ++r) {
                float c = fminf(fmaxf(acc[t][r] * rn, -1.0f + 1e-7f), 1.0f - 1e-7f);
                rs[t][r] += __expf(S_SCALE * c - 30.0f);   // exp(30c-30) <= 1
                acc[t][r] = 0.f;
            }
        sq = 0.f;
    }
#undef PHASE

    // ---- block epilogue: sum across 16 classes (lr lanes), store direct ----
#pragma unroll
    for (int t = 0; t < 3; ++t)
#pragma unroll
        for (int r = 0; r < 4; ++r) {
            float v = rs[t][r];
            v += __shfl_xor(v, 1); v += __shfl_xor(v, 2);
            v += __shfl_xor(v, 4); v += __shfl_xor(v, 8);
            if (lr == 0)
                partials[(long)bid * M_ROWS + (rg * 48 + t * 16 + q * 4 + r)] = v;
        }
}

// ---- deterministic reduce over GRID_M block partials per row ----
__global__ void k_reduce(const float* __restrict__ partials, float* __restrict__ sum_exp) {
    int r = blockIdx.x;              // 0..191
    float s = 0.0f;
    for (int i = threadIdx.x; i < GRID_M; i += 256)
        s += partials[(long)i * M_ROWS + r];
    s = wave_reduce_sum(s);
    __shared__ float wsm[4];
    int wid = threadIdx.x >> 6;
    if ((threadIdx.x & 63) == 0) wsm[wid] = s;
    __syncthreads();
    if (threadIdx.x == 0) sum_exp[r] = wsm[0] + wsm[1] + wsm[2] + wsm[3];
}

// ---- ce matrix, permutation argmin, final losses ----
__global__ void k_final(const float* __restrict__ sum_exp, const float* __restrict__ cosl,
                        const float* __restrict__ pred_ps, float* __restrict__ out) {
    int b = threadIdx.x;  // 0..63, one wave
    const int perms[6][3] = {{0,1,2},{0,2,1},{1,0,2},{1,2,0},{2,0,1},{2,1,0}};
    float ce[3][3];  // [n][s]
#pragma unroll
    for (int n = 0; n < 3; ++n) {
        float lse = 30.0f + logf(sum_exp[b * 3 + n]);
#pragma unroll
        for (int s = 0; s < 3; ++s) {
            float c  = cosl[(b * 3 + n) * 3 + s];
            float sl = sqrtf(fmaxf(1.0f - c * c, 1e-7f));
            float phi = c * COS_M - sl * SIN_M;
            phi = (c > TH_C) ? phi : (c - MM_C);
            float lm = lse + log1pf(expf(S_SCALE * phi - lse) - expf(S_SCALE * c - lse));
            ce[n][s] = lm - S_SCALE * phi;
        }
    }
    float best = 1e30f;
    int bp = 0;
#pragma unroll
    for (int p = 0; p < 6; ++p) {
        float cost = ce[perms[p][0]][0] + ce[perms[p][1]][1] + ce[perms[p][2]][2];
        if (cost < best) { best = cost; bp = p; }
    }
    float lspk = (ce[perms[bp][0]][0] + ce[perms[bp][1]][1] + ce[perms[bp][2]][2]) / 3.0f;

    float p0 = fminf(fmaxf(pred_ps[b * 4 + 0], 1e-6f), 1.0f - 1e-6f);
    float p1 = fminf(fmaxf(pred_ps[b * 4 + 1], 1e-6f), 1.0f - 1e-6f);
    float p2 = fminf(fmaxf(pred_ps[b * 4 + 2], 1e-6f), 1.0f - 1e-6f);
    float p3 = fminf(fmaxf(pred_ps[b * 4 + 3], 1e-6f), 1.0f - 1e-6f);
    float lcnt = -(log1pf(-p0) + log1pf(-p1) + log1pf(-p2) + logf(p3)) * 0.25f;

    float ts  = wave_reduce_sum(lspk) / 64.0f;
    float tcn = wave_reduce_sum(lcnt) / 64.0f;
    if (b == 0) {
        out[0] = ts + 0.1f * tcn;
        out[1] = ts;
        out[2] = tcn;
    }
}

extern "C" void kernel_launch(void* const* d_in, const int* in_sizes, int n_in,
                              void* d_out, int out_size, void* d_ws, size_t ws_size,
                              hipStream_t stream) {
    const float* pred_embs = (const float*)d_in[0];
    const float* pred_ps   = (const float*)d_in[1];
    const int*   gt_labels = (const int*)d_in[2];
    const float* weight    = (const float*)d_in[3];
    float* out = (float*)d_out;
    char*  ws  = (char*)d_ws;

    float*          xn       = (float*)(ws);                   // 147456 B
    unsigned short* xbf      = (unsigned short*)(ws + 147456); // 73728 B
    float*          cosl     = (float*)(ws + 221184);          // 2304 B
    float*          sum_exp  = (float*)(ws + 223488);          // 768 B
    float*          partials = (float*)(ws + 224256);          // 1024*192*4 = 786 KB

    k_normalize<<<M_ROWS, 64, 0, stream>>>(pred_embs, xn, xbf);
    k_main<<<GRID_M, 256, 0, stream>>>(weight, xbf, partials);
    k_gtcos<<<BATCH * NSLOT, 64, 0, stream>>>(weight, gt_labels, xn, cosl);
    k_reduce<<<M_ROWS, 256, 0, stream>>>(partials, sum_exp);
    k_final<<<1, 64, 0, stream>>>(sum_exp, cosl, pred_ps, out);
}

// Round 16
// 77.630 us; speedup vs baseline: 1.0014x; 1.0014x over previous
//
#include <hip/hip_runtime.h>
#include <hip/hip_bf16.h>
#include <math.h>

#define N_CLASS 200000
#define DIM     192
#define BATCH   64
#define NSLOT   3
#define M_ROWS  192            // B*N
#define GRID_M  1024           // 4 blocks x 256 CUs, all co-resident
// 12500 16-class tiles = 1024*12 + 212

#define S_SCALE 30.0f
#define COS_M   0.9800665778412416f
#define SIN_M   0.19866933079506122f
#define TH_C    (-0.9800665778412416f)
#define MM_C    0.039733866159012245f

typedef __attribute__((ext_vector_type(8))) short bf16x8;
typedef __attribute__((ext_vector_type(4))) float f32x4;

__device__ __forceinline__ float wave_reduce_sum(float v) {
#pragma unroll
    for (int o = 32; o > 0; o >>= 1) v += __shfl_xor(v, o, 64);
    return v;
}

__device__ __forceinline__ unsigned short f2bf(float f) {
    union { __hip_bfloat16 h; unsigned short u; } v;
    v.h = __float2bfloat16(f);
    return v.u;
}

__device__ __forceinline__ bf16x8 pack8(float4 a, float4 b) {
    bf16x8 r;
    r[0] = (short)f2bf(a.x); r[1] = (short)f2bf(a.y);
    r[2] = (short)f2bf(a.z); r[3] = (short)f2bf(a.w);
    r[4] = (short)f2bf(b.x); r[5] = (short)f2bf(b.y);
    r[6] = (short)f2bf(b.z); r[7] = (short)f2bf(b.w);
    return r;
}

__device__ __forceinline__ void gload_lds16(const void* g, void* l) {
    __builtin_amdgcn_global_load_lds(
        (const __attribute__((address_space(1))) unsigned int*)g,
        (__attribute__((address_space(3))) unsigned int*)l, 16, 0, 0);
}

// ---- normalize pred_embs -> xn fp32 [row][k] and xbf bf16 [row][k] ----
__global__ void k_normalize(const float* __restrict__ pe,
                            float* __restrict__ xn, unsigned short* __restrict__ xbf) {
    int r = blockIdx.x;      // 0..191
    int l = threadIdx.x;     // 0..63
    float v0 = pe[r * DIM + l];
    float v1 = pe[r * DIM + l + 64];
    float v2 = pe[r * DIM + l + 128];
    float ss = wave_reduce_sum(v0 * v0 + v1 * v1 + v2 * v2);
    float rn = 1.0f / fmaxf(sqrtf(ss), 1e-6f);
    float a0 = v0 * rn, a1 = v1 * rn, a2 = v2 * rn;
    xn[r * DIM + l]       = a0;
    xn[r * DIM + l + 64]  = a1;
    xn[r * DIM + l + 128] = a2;
    xbf[r * DIM + l]       = f2bf(a0);
    xbf[r * DIM + l + 64]  = f2bf(a1);
    xbf[r * DIM + l + 128] = f2bf(a2);
}

// ---- gt-label cosines in exact fp32 ----
__global__ void k_gtcos(const float* __restrict__ weight, const int* __restrict__ gt,
                        const float* __restrict__ xn, float* __restrict__ cosl) {
    int i = blockIdx.x;             // b*S + s
    int b = i / NSLOT, s = i - b * NSLOT;
    int l = threadIdx.x;
    int lab = gt[b * NSLOT + s];
    const float* w = weight + (long)lab * DIM;
    float w0 = w[l], w1 = w[l + 64], w2 = w[l + 128];
    float ss = wave_reduce_sum(w0 * w0 + w1 * w1 + w2 * w2);
    float rn = 1.0f / fmaxf(sqrtf(ss), 1e-6f);
    for (int n = 0; n < NSLOT; ++n) {
        const float* x = xn + (b * NSLOT + n) * DIM;
        float d = wave_reduce_sum(w0 * x[l] + w1 * x[l + 64] + w2 * x[l + 128]);
        float c = fminf(fmaxf(d * rn, -1.0f + 1e-7f), 1.0f - 1e-7f);
        if (l == 0) cosl[(b * NSLOT + n) * NSLOT + s] = c;
    }
}

// ---- MFMA GEMM: 256-thr blocks, 4 blocks/CU, W LDS ring-6 depth-5 ----
// Waves = 4 row-groups(48 rows) x 1 class-group(16 classes/tile).
// launch_bounds(256,2): no VGPR clamp. A-frags direct from global (once).
// W: ring-6 x 4KB, depth-5 counted vmcnt(4), 1 load/thread/phase.
// 4 resident blocks/CU interleave barrier stalls; 80 KB in flight/CU.
__global__ __launch_bounds__(256, 2)
void k_main(const float* __restrict__ weight,
            const unsigned short* __restrict__ xbf,
            float* __restrict__ partials) {
    __shared__ __align__(16) char smem[6 * 4096];   // 24 KB ring

    const int tid  = threadIdx.x;
    const int lane = tid & 63;
    const int rg   = tid >> 6;      // 0..3 -> rows rg*48..+47
    const int lr   = lane & 15;     // class in tile
    const int q    = lane >> 4;     // k-quad
    const int bid  = blockIdx.x;

    const int ntile = 12 + (bid < 212 ? 1 : 0);   // 12500 = 1024*12 + 212
    const int nst   = ntile * 3;

    // ---- A fragments direct from global (once) ----
    bf16x8 areg[3][6];
#pragma unroll
    for (int t = 0; t < 3; ++t) {
        const unsigned short* xp = xbf + (rg * 48 + t * 16 + lr) * DIM + q * 8;
#pragma unroll
        for (int s = 0; s < 6; ++s)
            areg[t][s] = *reinterpret_cast<const bf16x8*>(xp + s * 32);
    }

    // ---- W pipeline (depth 5, ring 6), tiles of 16 classes ----
    const int row_w = tid >> 4, pc_w = tid & 15;
    const long tstride = (long)GRID_M * 16 * DIM;  // floats between my tiles
    const float* gW0 = weight + (long)bid * 16 * DIM
                     + row_w * DIM + ((pc_w ^ (row_w & 7)) << 2);

    // prologue: issue phases 0..4 (tile kp: 0/0,0/1,0/2,1/0,1/1)
    gload_lds16(gW0,                  smem + 0 * 4096 + tid * 16);
    gload_lds16(gW0 + 64,             smem + 1 * 4096 + tid * 16);
    gload_lds16(gW0 + 128,            smem + 2 * 4096 + tid * 16);
    gload_lds16(gW0 + tstride,        smem + 3 * 4096 + tid * 16);
    gload_lds16(gW0 + tstride + 64,   smem + 4 * 4096 + tid * 16);
    long goff  = tstride + 128;                   // next issue: tile 1, kp 2
    int  kp_is = 2;
    int  si = 5, sc = 0;                          // issue slot, compute slot

    f32x4 acc[3];
#pragma unroll
    for (int t = 0; t < 3; ++t) acc[t] = (f32x4){0.f, 0.f, 0.f, 0.f};
    float rs[3][4];
#pragma unroll
    for (int t = 0; t < 3; ++t)
#pragma unroll
        for (int r = 0; r < 4; ++r) rs[t][r] = 0.f;
    float sq = 0.f;

    const int wrow16 = lr * 16;                    // float4 base of class row
    const int wx     = lr & 7;

#define PHASE(KP)                                                              \
    {                                                                          \
        int g = j * 3 + KP;                                                    \
        int rem = nst - 1 - g;                                                 \
        if (rem >= 4)      asm volatile("s_waitcnt vmcnt(4)" ::: "memory");    \
        else if (rem == 3) asm volatile("s_waitcnt vmcnt(3)" ::: "memory");    \
        else if (rem == 2) asm volatile("s_waitcnt vmcnt(2)" ::: "memory");    \
        else if (rem == 1) asm volatile("s_waitcnt vmcnt(1)" ::: "memory");    \
        else               asm volatile("s_waitcnt vmcnt(0)" ::: "memory");    \
        __builtin_amdgcn_s_barrier();                                          \
        __builtin_amdgcn_sched_barrier(0);                                     \
        if (g + 5 < nst) {                                                     \
            gload_lds16(gW0 + goff, smem + si * 4096 + tid * 16);              \
            si = (si == 5) ? 0 : si + 1;                                       \
            if (kp_is == 2) { kp_is = 0; goff += tstride - 128; }              \
            else            { ++kp_is;   goff += 64; }                         \
        }                                                                      \
        const float4* Wc = (const float4*)(smem + sc * 4096);                  \
        sc = (sc == 5) ? 0 : sc + 1;                                           \
        _Pragma("unroll")                                                      \
        for (int ks = 0; ks < 2; ++ks) {                                       \
            int c1 = ks * 8 + 2 * q;                                           \
            float4 wv1 = Wc[wrow16 + (c1 ^ wx)];                               \
            float4 wv2 = Wc[wrow16 + ((c1 + 1) ^ wx)];                         \
            sq += wv1.x*wv1.x + wv1.y*wv1.y + wv1.z*wv1.z + wv1.w*wv1.w        \
                + wv2.x*wv2.x + wv2.y*wv2.y + wv2.z*wv2.z + wv2.w*wv2.w;       \
            bf16x8 bb = pack8(wv1, wv2);                                       \
            acc[0] = __builtin_amdgcn_mfma_f32_16x16x32_bf16(                  \
                         areg[0][KP * 2 + ks], bb, acc[0], 0, 0, 0);           \
            acc[1] = __builtin_amdgcn_mfma_f32_16x16x32_bf16(                  \
                         areg[1][KP * 2 + ks], bb, acc[1], 0, 0, 0);           \
            acc[2] = __builtin_amdgcn_mfma_f32_16x16x32_bf16(                  \
                         areg[2][KP * 2 + ks], bb, acc[2], 0, 0, 0);           \
        }                                                                      \
    }

#pragma unroll 1
    for (int j = 0; j < ntile; ++j) {
        PHASE(0)
        PHASE(1)
        PHASE(2)
        // ---- per-tile epilogue: class norm + exp accumulation ----
        float s2 = sq;
        s2 += __shfl_xor(s2, 16); s2 += __shfl_xor(s2, 32);
        float rn = 1.0f / fmaxf(sqrtf(s2), 1e-6f);
#pragma unroll
        for (int t = 0; t < 3; ++t)
#pragma unroll
            for (int r = 0; r < 4; ++r) {
                float c = fminf(fmaxf(acc[t][r] * rn, -1.0f + 1e-7f), 1.0f - 1e-7f);
                rs[t][r] += __expf(S_SCALE * c - 30.0f);   // exp(30c-30) <= 1
                acc[t][r] = 0.f;
            }
        sq = 0.f;
    }
#undef PHASE

    // ---- block epilogue: sum across 16 classes (lr lanes), store direct ----
#pragma unroll
    for (int t = 0; t < 3; ++t)
#pragma unroll
        for (int r = 0; r < 4; ++r) {
            float v = rs[t][r];
            v += __shfl_xor(v, 1); v += __shfl_xor(v, 2);
            v += __shfl_xor(v, 4); v += __shfl_xor(v, 8);
            if (lr == 0)
                partials[(long)bid * M_ROWS + (rg * 48 + t * 16 + q * 4 + r)] = v;
        }
}

// ---- deterministic reduce over GRID_M block partials per row ----
__global__ void k_reduce(const float* __restrict__ partials, float* __restrict__ sum_exp) {
    int r = blockIdx.x;              // 0..191
    float s = 0.0f;
    for (int i = threadIdx.x; i < GRID_M; i += 256)
        s += partials[(long)i * M_ROWS + r];
    s = wave_reduce_sum(s);
    __shared__ float wsm[4];
    int wid = threadIdx.x >> 6;
    if ((threadIdx.x & 63) == 0) wsm[wid] = s;
    __syncthreads();
    if (threadIdx.x == 0) sum_exp[r] = wsm[0] + wsm[1] + wsm[2] + wsm[3];
}

// ---- ce matrix, permutation argmin, final losses ----
__global__ void k_final(const float* __restrict__ sum_exp, const float* __restrict__ cosl,
                        const float* __restrict__ pred_ps, float* __restrict__ out) {
    int b = threadIdx.x;  // 0..63, one wave
    const int perms[6][3] = {{0,1,2},{0,2,1},{1,0,2},{1,2,0},{2,0,1},{2,1,0}};
    float ce[3][3];  // [n][s]
#pragma unroll
    for (int n = 0; n < 3; ++n) {
        float lse = 30.0f + logf(sum_exp[b * 3 + n]);
#pragma unroll
        for (int s = 0; s < 3; ++s) {
            float c  = cosl[(b * 3 + n) * 3 + s];
            float sl = sqrtf(fmaxf(1.0f - c * c, 1e-7f));
            float phi = c * COS_M - sl * SIN_M;
            phi = (c > TH_C) ? phi : (c - MM_C);
            float lm = lse + log1pf(expf(S_SCALE * phi - lse) - expf(S_SCALE * c - lse));
            ce[n][s] = lm - S_SCALE * phi;
        }
    }
    float best = 1e30f;
    int bp = 0;
#pragma unroll
    for (int p = 0; p < 6; ++p) {
        float cost = ce[perms[p][0]][0] + ce[perms[p][1]][1] + ce[perms[p][2]][2];
        if (cost < best) { best = cost; bp = p; }
    }
    float lspk = (ce[perms[bp][0]][0] + ce[perms[bp][1]][1] + ce[perms[bp][2]][2]) / 3.0f;

    float p0 = fminf(fmaxf(pred_ps[b * 4 + 0], 1e-6f), 1.0f - 1e-6f);
    float p1 = fminf(fmaxf(pred_ps[b * 4 + 1], 1e-6f), 1.0f - 1e-6f);
    float p2 = fminf(fmaxf(pred_ps[b * 4 + 2], 1e-6f), 1.0f - 1e-6f);
    float p3 = fminf(fmaxf(pred_ps[b * 4 + 3], 1e-6f), 1.0f - 1e-6f);
    float lcnt = -(log1pf(-p0) + log1pf(-p1) + log1pf(-p2) + logf(p3)) * 0.25f;

    float ts  = wave_reduce_sum(lspk) / 64.0f;
    float tcn = wave_reduce_sum(lcnt) / 64.0f;
    if (b == 0) {
        out[0] = ts + 0.1f * tcn;
        out[1] = ts;
        out[2] = tcn;
    }
}

extern "C" void kernel_launch(void* const* d_in, const int* in_sizes, int n_in,
                              void* d_out, int out_size, void* d_ws, size_t ws_size,
                              hipStream_t stream) {
    const float* pred_embs = (const float*)d_in[0];
    const float* pred_ps   = (const float*)d_in[1];
    const int*   gt_labels = (const int*)d_in[2];
    const float* weight    = (const float*)d_in[3];
    float* out = (float*)d_out;
    char*  ws  = (char*)d_ws;

    float*          xn       = (float*)(ws);                   // 147456 B
    unsigned short* xbf      = (unsigned short*)(ws + 147456); // 73728 B
    float*          cosl     = (float*)(ws + 221184);          // 2304 B
    float*          sum_exp  = (float*)(ws + 223488);          // 768 B
    float*          partials = (float*)(ws + 224256);          // 1024*192*4 = 786 KB

    k_normalize<<<M_ROWS, 64, 0, stream>>>(pred_embs, xn, xbf);
    k_main<<<GRID_M, 256, 0, stream>>>(weight, xbf, partials);
    k_gtcos<<<BATCH * NSLOT, 64, 0, stream>>>(weight, gt_labels, xn, cosl);
    k_reduce<<<M_ROWS, 256, 0, stream>>>(partials, sum_exp);
    k_final<<<1, 64, 0, stream>>>(sum_exp, cosl, pred_ps, out);
}

// Round 17
// 57.275 us; speedup vs baseline: 1.3573x; 1.3554x over previous
//
#include <hip/hip_runtime.h>
#include <hip/hip_bf16.h>
#include <math.h>

#define N_CLASS 200000
#define DIM     192
#define BATCH   64
#define NSLOT   3
#define M_ROWS  192            // B*N
#define GRID_M  1024           // 4 blocks x 256 CUs, all co-resident
// 12500 16-class tiles = 1024*12 + 212

#define S_SCALE 30.0f
#define COS_M   0.9800665778412416f
#define SIN_M   0.19866933079506122f
#define TH_C    (-0.9800665778412416f)
#define MM_C    0.039733866159012245f

typedef __attribute__((ext_vector_type(8))) short bf16x8;
typedef __attribute__((ext_vector_type(4))) float f32x4;

__device__ __forceinline__ float wave_reduce_sum(float v) {
#pragma unroll
    for (int o = 32; o > 0; o >>= 1) v += __shfl_xor(v, o, 64);
    return v;
}

__device__ __forceinline__ unsigned short f2bf(float f) {
    union { __hip_bfloat16 h; unsigned short u; } v;
    v.h = __float2bfloat16(f);
    return v.u;
}

__device__ __forceinline__ bf16x8 pack8(float4 a, float4 b) {
    bf16x8 r;
    r[0] = (short)f2bf(a.x); r[1] = (short)f2bf(a.y);
    r[2] = (short)f2bf(a.z); r[3] = (short)f2bf(a.w);
    r[4] = (short)f2bf(b.x); r[5] = (short)f2bf(b.y);
    r[6] = (short)f2bf(b.z); r[7] = (short)f2bf(b.w);
    return r;
}

// ---- normalize pred_embs -> xn fp32 [row][k] and xbf bf16 [row][k] ----
__global__ void k_normalize(const float* __restrict__ pe,
                            float* __restrict__ xn, unsigned short* __restrict__ xbf) {
    int r = blockIdx.x;      // 0..191
    int l = threadIdx.x;     // 0..63
    float v0 = pe[r * DIM + l];
    float v1 = pe[r * DIM + l + 64];
    float v2 = pe[r * DIM + l + 128];
    float ss = wave_reduce_sum(v0 * v0 + v1 * v1 + v2 * v2);
    float rn = 1.0f / fmaxf(sqrtf(ss), 1e-6f);
    float a0 = v0 * rn, a1 = v1 * rn, a2 = v2 * rn;
    xn[r * DIM + l]       = a0;
    xn[r * DIM + l + 64]  = a1;
    xn[r * DIM + l + 128] = a2;
    xbf[r * DIM + l]       = f2bf(a0);
    xbf[r * DIM + l + 64]  = f2bf(a1);
    xbf[r * DIM + l + 128] = f2bf(a2);
}

// ---- gt-label cosines in exact fp32 ----
__global__ void k_gtcos(const float* __restrict__ weight, const int* __restrict__ gt,
                        const float* __restrict__ xn, float* __restrict__ cosl) {
    int i = blockIdx.x;             // b*S + s
    int b = i / NSLOT, s = i - b * NSLOT;
    int l = threadIdx.x;
    int lab = gt[b * NSLOT + s];
    const float* w = weight + (long)lab * DIM;
    float w0 = w[l], w1 = w[l + 64], w2 = w[l + 128];
    float ss = wave_reduce_sum(w0 * w0 + w1 * w1 + w2 * w2);
    float rn = 1.0f / fmaxf(sqrtf(ss), 1e-6f);
    for (int n = 0; n < NSLOT; ++n) {
        const float* x = xn + (b * NSLOT + n) * DIM;
        float d = wave_reduce_sum(w0 * x[l] + w1 * x[l + 64] + w2 * x[l + 128]);
        float c = fminf(fmaxf(d * rn, -1.0f + 1e-7f), 1.0f - 1e-7f);
        if (l == 0) cosl[(b * NSLOT + n) * NSLOT + s] = c;
    }
}

// ---- MFMA GEMM: contiguous 4KB wave-loads of W, LDS transpose, 4 blk/CU ----
// 256 thr = 4 waves = 4 row-groups(48 rows) x 1 class-group(16 classes/tile).
// Per 12KB tile: 3 contiguous global_load_dwordx4/thread (copy-shaped) ->
// regs -> ds_write_b128 transposed [col][row] with +1 f4 pad (bank-optimal
// both sides) -> 12 ds_read frags + 18 MFMA. One barrier per tile, next
// tile prefetched into regs under the MFMA block. Ring-2 LDS (25.5 KB).
__global__ __launch_bounds__(256, 2)
void k_main(const float* __restrict__ weight,
            const unsigned short* __restrict__ xbf,
            float* __restrict__ partials) {
    __shared__ __align__(16) float4 wtile[2][48 * 17 + 1];   // 2 x 12.77 KB

    const int tid  = threadIdx.x;
    const int lane = tid & 63;
    const int rg   = tid >> 6;      // 0..3 -> rows rg*48..+47
    const int lr   = lane & 15;     // class in tile
    const int q    = lane >> 4;     // k-quad
    const int bid  = blockIdx.x;

    const int ntile = 12 + (bid < 212 ? 1 : 0);   // 12500 = 1024*12 + 212

    // ---- A fragments direct from global (once) ----
    bf16x8 areg[3][6];
#pragma unroll
    for (int t = 0; t < 3; ++t) {
        const unsigned short* xp = xbf + (rg * 48 + t * 16 + lr) * DIM + q * 8;
#pragma unroll
        for (int s = 0; s < 6; ++s)
            areg[t][s] = *reinterpret_cast<const bf16x8*>(xp + s * 32);
    }

    // ---- transpose-write slots: f4 f=(p*256+tid) -> (row=f/48,col=f%48) ----
    int wr0, wr1, wr2;
    {
        int f0 = tid,       r0 = f0 / 48, c0 = f0 - r0 * 48;
        int f1 = tid + 256, r1 = f1 / 48, c1 = f1 - r1 * 48;
        int f2 = tid + 512, r2 = f2 / 48, c2 = f2 - r2 * 48;
        wr0 = c0 * 17 + r0; wr1 = c1 * 17 + r1; wr2 = c2 * 17 + r2;
    }

    // tile j of this block = global tile (j*GRID_M + bid); 768 f4 per tile
    const float4* gW = reinterpret_cast<const float4*>(weight) + (long)bid * 768 + tid;
    const long tstep4 = (long)GRID_M * 768;

    // prologue: tile 0 into regs (3 contiguous 4KB wave-loads)
    float4 st0 = gW[0], st1 = gW[256], st2 = gW[512];
    gW += tstep4;

    f32x4 acc[3];
#pragma unroll
    for (int t = 0; t < 3; ++t) acc[t] = (f32x4){0.f, 0.f, 0.f, 0.f};
    float rs[3][4];
#pragma unroll
    for (int t = 0; t < 3; ++t)
#pragma unroll
        for (int r = 0; r < 4; ++r) rs[t][r] = 0.f;

    const int rbase = 34 * q + lr;       // frag read: idx = 136*s + rbase (+17)

#pragma unroll 1
    for (int j = 0; j < ntile; ++j) {
        float4* buf = &wtile[j & 1][0];
        // stage regs -> LDS (compiler inserts precise vmcnt for st* deps)
        buf[wr0] = st0; buf[wr1] = st1; buf[wr2] = st2;
        asm volatile("s_waitcnt lgkmcnt(0)" ::: "memory");   // writes visible
        __builtin_amdgcn_s_barrier();
        __builtin_amdgcn_sched_barrier(0);
        // prefetch next tile into regs (hidden under MFMA block)
        if (j + 1 < ntile) {
            st0 = gW[0]; st1 = gW[256]; st2 = gW[512];
            gW += tstep4;
        }
        float sq = 0.f;
#pragma unroll
        for (int s = 0; s < 6; ++s) {
            float4 wv1 = buf[136 * s + rbase];        // class lr, dims 8q+32s..
            float4 wv2 = buf[136 * s + rbase + 17];   // dims 8q+4+32s..
            sq += wv1.x*wv1.x + wv1.y*wv1.y + wv1.z*wv1.z + wv1.w*wv1.w
                + wv2.x*wv2.x + wv2.y*wv2.y + wv2.z*wv2.z + wv2.w*wv2.w;
            bf16x8 bb = pack8(wv1, wv2);
            acc[0] = __builtin_amdgcn_mfma_f32_16x16x32_bf16(areg[0][s], bb, acc[0], 0, 0, 0);
            acc[1] = __builtin_amdgcn_mfma_f32_16x16x32_bf16(areg[1][s], bb, acc[1], 0, 0, 0);
            acc[2] = __builtin_amdgcn_mfma_f32_16x16x32_bf16(areg[2][s], bb, acc[2], 0, 0, 0);
        }
        // ---- per-tile epilogue: class norm + exp accumulation ----
        sq += __shfl_xor(sq, 16); sq += __shfl_xor(sq, 32);
        float rn = 1.0f / fmaxf(sqrtf(sq), 1e-6f);
#pragma unroll
        for (int t = 0; t < 3; ++t)
#pragma unroll
            for (int r = 0; r < 4; ++r) {
                float c = fminf(fmaxf(acc[t][r] * rn, -1.0f + 1e-7f), 1.0f - 1e-7f);
                rs[t][r] += __expf(S_SCALE * c - 30.0f);   // exp(30c-30) <= 1
                acc[t][r] = 0.f;
            }
    }

    // ---- block epilogue: sum across 16 classes (lr lanes), store direct ----
#pragma unroll
    for (int t = 0; t < 3; ++t)
#pragma unroll
        for (int r = 0; r < 4; ++r) {
            float v = rs[t][r];
            v += __shfl_xor(v, 1); v += __shfl_xor(v, 2);
            v += __shfl_xor(v, 4); v += __shfl_xor(v, 8);
            if (lr == 0)
                partials[(long)bid * M_ROWS + (rg * 48 + t * 16 + q * 4 + r)] = v;
        }
}

// ---- deterministic reduce over GRID_M block partials per row ----
__global__ void k_reduce(const float* __restrict__ partials, float* __restrict__ sum_exp) {
    int r = blockIdx.x;              // 0..191
    float s = 0.0f;
    for (int i = threadIdx.x; i < GRID_M; i += 256)
        s += partials[(long)i * M_ROWS + r];
    s = wave_reduce_sum(s);
    __shared__ float wsm[4];
    int wid = threadIdx.x >> 6;
    if ((threadIdx.x & 63) == 0) wsm[wid] = s;
    __syncthreads();
    if (threadIdx.x == 0) sum_exp[r] = wsm[0] + wsm[1] + wsm[2] + wsm[3];
}

// ---- ce matrix, permutation argmin, final losses ----
__global__ void k_final(const float* __restrict__ sum_exp, const float* __restrict__ cosl,
                        const float* __restrict__ pred_ps, float* __restrict__ out) {
    int b = threadIdx.x;  // 0..63, one wave
    const int perms[6][3] = {{0,1,2},{0,2,1},{1,0,2},{1,2,0},{2,0,1},{2,1,0}};
    float ce[3][3];  // [n][s]
#pragma unroll
    for (int n = 0; n < 3; ++n) {
        float lse = 30.0f + logf(sum_exp[b * 3 + n]);
#pragma unroll
        for (int s = 0; s < 3; ++s) {
            float c  = cosl[(b * 3 + n) * 3 + s];
            float sl = sqrtf(fmaxf(1.0f - c * c, 1e-7f));
            float phi = c * COS_M - sl * SIN_M;
            phi = (c > TH_C) ? phi : (c - MM_C);
            float lm = lse + log1pf(expf(S_SCALE * phi - lse) - expf(S_SCALE * c - lse));
            ce[n][s] = lm - S_SCALE * phi;
        }
    }
    float best = 1e30f;
    int bp = 0;
#pragma unroll
    for (int p = 0; p < 6; ++p) {
        float cost = ce[perms[p][0]][0] + ce[perms[p][1]][1] + ce[perms[p][2]][2];
        if (cost < best) { best = cost; bp = p; }
    }
    float lspk = (ce[perms[bp][0]][0] + ce[perms[bp][1]][1] + ce[perms[bp][2]][2]) / 3.0f;

    float p0 = fminf(fmaxf(pred_ps[b * 4 + 0], 1e-6f), 1.0f - 1e-6f);
    float p1 = fminf(fmaxf(pred_ps[b * 4 + 1], 1e-6f), 1.0f - 1e-6f);
    float p2 = fminf(fmaxf(pred_ps[b * 4 + 2], 1e-6f), 1.0f - 1e-6f);
    float p3 = fminf(fmaxf(pred_ps[b * 4 + 3], 1e-6f), 1.0f - 1e-6f);
    float lcnt = -(log1pf(-p0) + log1pf(-p1) + log1pf(-p2) + logf(p3)) * 0.25f;

    float ts  = wave_reduce_sum(lspk) / 64.0f;
    float tcn = wave_reduce_sum(lcnt) / 64.0f;
    if (b == 0) {
        out[0] = ts + 0.1f * tcn;
        out[1] = ts;
        out[2] = tcn;
    }
}

extern "C" void kernel_launch(void* const* d_in, const int* in_sizes, int n_in,
                              void* d_out, int out_size, void* d_ws, size_t ws_size,
                              hipStream_t stream) {
    const float* pred_embs = (const float*)d_in[0];
    const float* pred_ps   = (const float*)d_in[1];
    const int*   gt_labels = (const int*)d_in[2];
    const float* weight    = (const float*)d_in[3];
    float* out = (float*)d_out;
    char*  ws  = (char*)d_ws;

    float*          xn       = (float*)(ws);                   // 147456 B
    unsigned short* xbf      = (unsigned short*)(ws + 147456); // 73728 B
    float*          cosl     = (float*)(ws + 221184);          // 2304 B
    float*          sum_exp  = (float*)(ws + 223488);          // 768 B
    float*          partials = (float*)(ws + 224256);          // 1024*192*4 = 786 KB

    k_normalize<<<M_ROWS, 64, 0, stream>>>(pred_embs, xn, xbf);
    k_main<<<GRID_M, 256, 0, stream>>>(weight, xbf, partials);
    k_gtcos<<<BATCH * NSLOT, 64, 0, stream>>>(weight, gt_labels, xn, cosl);
    k_reduce<<<M_ROWS, 256, 0, stream>>>(partials, sum_exp);
    k_final<<<1, 64, 0, stream>>>(sum_exp, cosl, pred_ps, out);
}

// Round 18
// 56.427 us; speedup vs baseline: 1.3777x; 1.0150x over previous
//
#include <hip/hip_runtime.h>
#include <hip/hip_bf16.h>
#include <math.h>

#define N_CLASS 200000
#define DIM     192
#define BATCH   64
#define NSLOT   3
#define M_ROWS  192            // B*N
#define GRID_M  1024           // 4 blocks x 256 CUs, all co-resident
// 12500 16-class tiles = 1024*12 + 212

#define S_SCALE 30.0f
#define COS_M   0.9800665778412416f
#define SIN_M   0.19866933079506122f
#define TH_C    (-0.9800665778412416f)
#define MM_C    0.039733866159012245f

typedef __attribute__((ext_vector_type(8))) short bf16x8;
typedef __attribute__((ext_vector_type(4))) float f32x4;

__device__ __forceinline__ float wave_reduce_sum(float v) {
#pragma unroll
    for (int o = 32; o > 0; o >>= 1) v += __shfl_xor(v, o, 64);
    return v;
}

__device__ __forceinline__ unsigned short f2bf(float f) {
    union { __hip_bfloat16 h; unsigned short u; } v;
    v.h = __float2bfloat16(f);
    return v.u;
}

__device__ __forceinline__ bf16x8 pack8(float4 a, float4 b) {
    bf16x8 r;
    r[0] = (short)f2bf(a.x); r[1] = (short)f2bf(a.y);
    r[2] = (short)f2bf(a.z); r[3] = (short)f2bf(a.w);
    r[4] = (short)f2bf(b.x); r[5] = (short)f2bf(b.y);
    r[6] = (short)f2bf(b.z); r[7] = (short)f2bf(b.w);
    return r;
}

// ---- normalize pred_embs -> xn fp32 [row][k] and xbf bf16 [row][k] ----
__global__ void k_normalize(const float* __restrict__ pe,
                            float* __restrict__ xn, unsigned short* __restrict__ xbf) {
    int r = blockIdx.x;      // 0..191
    int l = threadIdx.x;     // 0..63
    float v0 = pe[r * DIM + l];
    float v1 = pe[r * DIM + l + 64];
    float v2 = pe[r * DIM + l + 128];
    float ss = wave_reduce_sum(v0 * v0 + v1 * v1 + v2 * v2);
    float rn = 1.0f / fmaxf(sqrtf(ss), 1e-6f);
    float a0 = v0 * rn, a1 = v1 * rn, a2 = v2 * rn;
    xn[r * DIM + l]       = a0;
    xn[r * DIM + l + 64]  = a1;
    xn[r * DIM + l + 128] = a2;
    xbf[r * DIM + l]       = f2bf(a0);
    xbf[r * DIM + l + 64]  = f2bf(a1);
    xbf[r * DIM + l + 128] = f2bf(a2);
}

// ---- gt-label cosines in exact fp32 ----
__global__ void k_gtcos(const float* __restrict__ weight, const int* __restrict__ gt,
                        const float* __restrict__ xn, float* __restrict__ cosl) {
    int i = blockIdx.x;             // b*S + s
    int b = i / NSLOT, s = i - b * NSLOT;
    int l = threadIdx.x;
    int lab = gt[b * NSLOT + s];
    const float* w = weight + (long)lab * DIM;
    float w0 = w[l], w1 = w[l + 64], w2 = w[l + 128];
    float ss = wave_reduce_sum(w0 * w0 + w1 * w1 + w2 * w2);
    float rn = 1.0f / fmaxf(sqrtf(ss), 1e-6f);
    for (int n = 0; n < NSLOT; ++n) {
        const float* x = xn + (b * NSLOT + n) * DIM;
        float d = wave_reduce_sum(w0 * x[l] + w1 * x[l + 64] + w2 * x[l + 128]);
        float c = fminf(fmaxf(d * rn, -1.0f + 1e-7f), 1.0f - 1e-7f);
        if (l == 0) cosl[(b * NSLOT + n) * NSLOT + s] = c;
    }
}

// ---- MFMA GEMM: contiguous 4KB-burst W loads, depth-2 reg prefetch ----
// 256 thr = 4 waves = 4 row-groups(48 rows) x 16 classes/tile.
// Per 12KB tile: 3 contiguous 1KB wave-loads -> regs (issued 2 TILES ahead
// of their ds_write, gap > HBM latency) -> LDS transpose [col][row] +1 pad
// -> 12 ds_read frags + 18 MFMA + exp epilogue. Ring-2 LDS, 1 barrier/tile.
__global__ __launch_bounds__(256, 2)
void k_main(const float* __restrict__ weight,
            const unsigned short* __restrict__ xbf,
            float* __restrict__ partials) {
    __shared__ __align__(16) float4 wtile[2][48 * 17 + 1];   // 2 x 12.77 KB

    const int tid  = threadIdx.x;
    const int lane = tid & 63;
    const int rg   = tid >> 6;      // 0..3 -> rows rg*48..+47
    const int lr   = lane & 15;     // class in tile
    const int q    = lane >> 4;     // k-quad
    const int bid  = blockIdx.x;

    const int ntile = 12 + (bid < 212 ? 1 : 0);   // 12500 = 1024*12 + 212

    // ---- A fragments direct from global (once) ----
    bf16x8 areg[3][6];
#pragma unroll
    for (int t = 0; t < 3; ++t) {
        const unsigned short* xp = xbf + (rg * 48 + t * 16 + lr) * DIM + q * 8;
#pragma unroll
        for (int s = 0; s < 6; ++s)
            areg[t][s] = *reinterpret_cast<const bf16x8*>(xp + s * 32);
    }

    // ---- transpose-write slots: f4 f=(p*256+tid) -> (row=f/48,col=f%48) ----
    int wr0, wr1, wr2;
    {
        int f0 = tid,       r0 = f0 / 48, c0 = f0 - r0 * 48;
        int f1 = tid + 256, r1 = f1 / 48, c1 = f1 - r1 * 48;
        int f2 = tid + 512, r2 = f2 / 48, c2 = f2 - r2 * 48;
        wr0 = c0 * 17 + r0; wr1 = c1 * 17 + r1; wr2 = c2 * 17 + r2;
    }

    const float4* gW = reinterpret_cast<const float4*>(weight) + (long)bid * 768 + tid;
    const long tstep4 = (long)GRID_M * 768;

    // prologue: tiles 0,1 into two register sets (depth-2)
    float4 sa0 = gW[0], sa1 = gW[256], sa2 = gW[512];
    gW += tstep4;
    float4 sb0 = gW[0], sb1 = gW[256], sb2 = gW[512];
    gW += tstep4;

    f32x4 acc[3];
#pragma unroll
    for (int t = 0; t < 3; ++t) acc[t] = (f32x4){0.f, 0.f, 0.f, 0.f};
    float rs[3][4];
#pragma unroll
    for (int t = 0; t < 3; ++t)
#pragma unroll
        for (int r = 0; r < 4; ++r) rs[t][r] = 0.f;

    const int rbase = 34 * q + lr;       // frag read: idx = 136*s + rbase (+17)

#define COMPUTE(bufp)                                                          \
    {                                                                          \
        float sq = 0.f;                                                        \
        _Pragma("unroll")                                                      \
        for (int s = 0; s < 6; ++s) {                                          \
            float4 wv1 = (bufp)[136 * s + rbase];                              \
            float4 wv2 = (bufp)[136 * s + rbase + 17];                         \
            sq += wv1.x*wv1.x + wv1.y*wv1.y + wv1.z*wv1.z + wv1.w*wv1.w        \
                + wv2.x*wv2.x + wv2.y*wv2.y + wv2.z*wv2.z + wv2.w*wv2.w;       \
            bf16x8 bb = pack8(wv1, wv2);                                       \
            acc[0] = __builtin_amdgcn_mfma_f32_16x16x32_bf16(areg[0][s], bb, acc[0], 0, 0, 0); \
            acc[1] = __builtin_amdgcn_mfma_f32_16x16x32_bf16(areg[1][s], bb, acc[1], 0, 0, 0); \
            acc[2] = __builtin_amdgcn_mfma_f32_16x16x32_bf16(areg[2][s], bb, acc[2], 0, 0, 0); \
        }                                                                      \
        sq += __shfl_xor(sq, 16); sq += __shfl_xor(sq, 32);                    \
        float rn = 1.0f / fmaxf(sqrtf(sq), 1e-6f);                             \
        _Pragma("unroll")                                                      \
        for (int t = 0; t < 3; ++t)                                            \
            _Pragma("unroll")                                                  \
            for (int r = 0; r < 4; ++r) {                                      \
                float c = fminf(fmaxf(acc[t][r] * rn, -1.0f + 1e-7f), 1.0f - 1e-7f); \
                rs[t][r] += __expf(S_SCALE * c - 30.0f);                       \
                acc[t][r] = 0.f;                                               \
            }                                                                  \
    }

    const int npair = ntile >> 1;
#pragma unroll 1
    for (int p = 0; p < npair; ++p) {
        // ---- even tile 2p: buffer 0, set A ----
        {
            float4* buf = &wtile[0][0];
            buf[wr0] = sa0; buf[wr1] = sa1; buf[wr2] = sa2;
            asm volatile("s_waitcnt lgkmcnt(0)" ::: "memory");
            __builtin_amdgcn_s_barrier();
            __builtin_amdgcn_sched_barrier(0);
            if (2 * p + 2 < ntile) {          // reload set A for tile 2p+2
                sa0 = gW[0]; sa1 = gW[256]; sa2 = gW[512];
                gW += tstep4;
            }
            COMPUTE(buf)
        }
        // ---- odd tile 2p+1: buffer 1, set B ----
        {
            float4* buf = &wtile[1][0];
            buf[wr0] = sb0; buf[wr1] = sb1; buf[wr2] = sb2;
            asm volatile("s_waitcnt lgkmcnt(0)" ::: "memory");
            __builtin_amdgcn_s_barrier();
            __builtin_amdgcn_sched_barrier(0);
            if (2 * p + 3 < ntile) {          // reload set B for tile 2p+3
                sb0 = gW[0]; sb1 = gW[256]; sb2 = gW[512];
                gW += tstep4;
            }
            COMPUTE(buf)
        }
    }
    if (ntile & 1) {                          // tail tile (set A, buffer 0)
        float4* buf = &wtile[0][0];
        buf[wr0] = sa0; buf[wr1] = sa1; buf[wr2] = sa2;
        asm volatile("s_waitcnt lgkmcnt(0)" ::: "memory");
        __builtin_amdgcn_s_barrier();
        __builtin_amdgcn_sched_barrier(0);
        COMPUTE(buf)
    }
#undef COMPUTE

    // ---- block epilogue: sum across 16 classes; [row][block] layout ----
#pragma unroll
    for (int t = 0; t < 3; ++t)
#pragma unroll
        for (int r = 0; r < 4; ++r) {
            float v = rs[t][r];
            v += __shfl_xor(v, 1); v += __shfl_xor(v, 2);
            v += __shfl_xor(v, 4); v += __shfl_xor(v, 8);
            if (lr == 0)
                partials[(long)(rg * 48 + t * 16 + q * 4 + r) * GRID_M + bid] = v;
        }
}

// ---- deterministic reduce: row r = partials[r*GRID_M ..], coalesced f4 ----
__global__ void k_reduce(const float* __restrict__ partials, float* __restrict__ sum_exp) {
    int r = blockIdx.x;              // 0..191
    float4 v = reinterpret_cast<const float4*>(partials + (long)r * GRID_M)[threadIdx.x];
    float s = v.x + v.y + v.z + v.w;
    s = wave_reduce_sum(s);
    __shared__ float wsm[4];
    int wid = threadIdx.x >> 6;
    if ((threadIdx.x & 63) == 0) wsm[wid] = s;
    __syncthreads();
    if (threadIdx.x == 0) sum_exp[r] = wsm[0] + wsm[1] + wsm[2] + wsm[3];
}

// ---- ce matrix, permutation argmin, final losses ----
__global__ void k_final(const float* __restrict__ sum_exp, const float* __restrict__ cosl,
                        const float* __restrict__ pred_ps, float* __restrict__ out) {
    int b = threadIdx.x;  // 0..63, one wave
    const int perms[6][3] = {{0,1,2},{0,2,1},{1,0,2},{1,2,0},{2,0,1},{2,1,0}};
    float ce[3][3];  // [n][s]
#pragma unroll
    for (int n = 0; n < 3; ++n) {
        float lse = 30.0f + logf(sum_exp[b * 3 + n]);
#pragma unroll
        for (int s = 0; s < 3; ++s) {
            float c  = cosl[(b * 3 + n) * 3 + s];
            float sl = sqrtf(fmaxf(1.0f - c * c, 1e-7f));
            float phi = c * COS_M - sl * SIN_M;
            phi = (c > TH_C) ? phi : (c - MM_C);
            float lm = lse + log1pf(expf(S_SCALE * phi - lse) - expf(S_SCALE * c - lse));
            ce[n][s] = lm - S_SCALE * phi;
        }
    }
    float best = 1e30f;
    int bp = 0;
#pragma unroll
    for (int p = 0; p < 6; ++p) {
        float cost = ce[perms[p][0]][0] + ce[perms[p][1]][1] + ce[perms[p][2]][2];
        if (cost < best) { best = cost; bp = p; }
    }
    float lspk = (ce[perms[bp][0]][0] + ce[perms[bp][1]][1] + ce[perms[bp][2]][2]) / 3.0f;

    float p0 = fminf(fmaxf(pred_ps[b * 4 + 0], 1e-6f), 1.0f - 1e-6f);
    float p1 = fminf(fmaxf(pred_ps[b * 4 + 1], 1e-6f), 1.0f - 1e-6f);
    float p2 = fminf(fmaxf(pred_ps[b * 4 + 2], 1e-6f), 1.0f - 1e-6f);
    float p3 = fminf(fmaxf(pred_ps[b * 4 + 3], 1e-6f), 1.0f - 1e-6f);
    float lcnt = -(log1pf(-p0) + log1pf(-p1) + log1pf(-p2) + logf(p3)) * 0.25f;

    float ts  = wave_reduce_sum(lspk) / 64.0f;
    float tcn = wave_reduce_sum(lcnt) / 64.0f;
    if (b == 0) {
        out[0] = ts + 0.1f * tcn;
        out[1] = ts;
        out[2] = tcn;
    }
}

extern "C" void kernel_launch(void* const* d_in, const int* in_sizes, int n_in,
                              void* d_out, int out_size, void* d_ws, size_t ws_size,
                              hipStream_t stream) {
    const float* pred_embs = (const float*)d_in[0];
    const float* pred_ps   = (const float*)d_in[1];
    const int*   gt_labels = (const int*)d_in[2];
    const float* weight    = (const float*)d_in[3];
    float* out = (float*)d_out;
    char*  ws  = (char*)d_ws;

    float*          xn       = (float*)(ws);                   // 147456 B
    unsigned short* xbf      = (unsigned short*)(ws + 147456); // 73728 B
    float*          cosl     = (float*)(ws + 221184);          // 2304 B
    float*          sum_exp  = (float*)(ws + 223488);          // 768 B
    float*          partials = (float*)(ws + 224256);          // 192*1024*4 = 786 KB

    k_normalize<<<M_ROWS, 64, 0, stream>>>(pred_embs, xn, xbf);
    k_main<<<GRID_M, 256, 0, stream>>>(weight, xbf, partials);
    k_gtcos<<<BATCH * NSLOT, 64, 0, stream>>>(weight, gt_labels, xn, cosl);
    k_reduce<<<M_ROWS, 256, 0, stream>>>(partials, sum_exp);
    k_final<<<1, 64, 0, stream>>>(sum_exp, cosl, pred_ps, out);
}